// Round 6
// baseline (207.048 us; speedup 1.0000x reference)
//
#include <hip/hip_runtime.h>
#include <stdint.h>

#define NTOT 8192
#define BHALF 4096
#define DZ 512
#define DC 128
#define TEMPV 0.5f
#define FIXM 16.0f
#define LOG2E 1.44269504f
#define FM2 23.08312065f   // FIXM * LOG2E
#define SCALE1 0x7F7F7F7F  // e8m0 unit scales

typedef __attribute__((ext_vector_type(4))) float f32x4;
typedef __attribute__((ext_vector_type(4))) float floatx4;
typedef __attribute__((ext_vector_type(2))) float float2v;
typedef __attribute__((ext_vector_type(2))) unsigned long ulong2v;  // 16B chunk
typedef __attribute__((ext_vector_type(8))) int int8v;              // 32B MFMA operand
typedef __attribute__((ext_vector_type(4))) unsigned int uint4v;

// MX-scaled fp8 MFMA, K=128, unit scales. cbsz=0/blgp=0 -> FP8 e4m3 A and B.
#define MFMAS(a, b, c) \
  __builtin_amdgcn_mfma_scale_f32_16x16x128_f8f6f4((a), (b), (c), 0, 0, 0, SCALE1, 0, SCALE1)

__device__ __forceinline__ uint32_t pk4_e4m3(float f0, float f1, float f2, float f3) {
  int w = 0;
  w = __builtin_amdgcn_cvt_pk_fp8_f32(f0, f1, w, false);
  w = __builtin_amdgcn_cvt_pk_fp8_f32(f2, f3, w, true);
  return (uint32_t)w;
}

__device__ __forceinline__ int8v mk8(ulong2v lo, ulong2v hi) {
  int8v r;
  ((ulong2v*)&r)[0] = lo;
  ((ulong2v*)&r)[1] = hi;
  return r;
}

// ---------------- convert: fp32 -> fp8 e4m3 (frag-pair-tiled) + fused pos dots ----------------
// R21 single-pass version (verified): one wave per pair-row p; z read once; pos dot via
// shfl_xor(.,32) cross-half products. c-section unchanged verified mapping.
__global__ void convert_kernel(const float* __restrict__ z_i, const float* __restrict__ z_j,
                               const float* __restrict__ c_i, const float* __restrict__ c_j,
                               uint8_t* __restrict__ zbT, uint8_t* __restrict__ cbT,
                               float* __restrict__ pos2, float* __restrict__ out) {
  if (blockIdx.x < 1024) {
    const int p    = blockIdx.x * 4 + (threadIdx.x >> 6);   // 0..4095
    const int lane = threadIdx.x & 63;
    const int half = lane >> 5;          // 0: z_i row p, 1: z_j row p (global row p+4096)
    const int l    = lane & 31;
    const int cc   = l >> 2;
    const int lq   = l & 3;
    const int k0   = cc * 64 + lq * 8;

    const float* src = half ? (z_j + (size_t)p * DZ) : (z_i + (size_t)p * DZ);
    floatx4 a0 = *(const floatx4*)(src + k0);
    floatx4 a1 = *(const floatx4*)(src + k0 + 4);
    floatx4 b0 = *(const floatx4*)(src + k0 + 32);
    floatx4 b1 = *(const floatx4*)(src + k0 + 36);

    uint4v o;
    o.x = pk4_e4m3(a0[0], a0[1], a0[2], a0[3]);
    o.y = pk4_e4m3(a1[0], a1[1], a1[2], a1[3]);
    o.z = pk4_e4m3(b0[0], b0[1], b0[2], b0[3]);
    o.w = pk4_e4m3(b1[0], b1[1], b1[2], b1[3]);
    const int row = half ? (p + BHALF) : p;
    const size_t ci = (((size_t)(row >> 4) * 8 + cc) * 64 + (size_t)lq * 16 + (row & 15));
    *(uint4v*)(zbT + ci * 16) = o;

    float d = 0.0f;
#pragma unroll
    for (int m = 0; m < 4; ++m) d = __builtin_fmaf(a0[m], __shfl_xor(a0[m], 32), d);
#pragma unroll
    for (int m = 0; m < 4; ++m) d = __builtin_fmaf(a1[m], __shfl_xor(a1[m], 32), d);
#pragma unroll
    for (int m = 0; m < 4; ++m) d = __builtin_fmaf(b0[m], __shfl_xor(b0[m], 32), d);
#pragma unroll
    for (int m = 0; m < 4; ++m) d = __builtin_fmaf(b1[m], __shfl_xor(b1[m], 32), d);
#pragma unroll
    for (int off = 1; off < 32; off <<= 1) d += __shfl_xor(d, off);
    if (lane == 0) pos2[p] = 2.0f * d;
    return;
  }

  // c-section: blocks 1024..1279, verified chunk mapping (i2 in [0, 65536))
  if (blockIdx.x == 1024 && threadIdx.x == 0) out[0] = 0.0f;
  const int i2   = (blockIdx.x - 1024) * 256 + threadIdx.x;
  const int lane = i2 & 63, g = i2 >> 6;
  const int ct = g >> 1, cc = g & 1;
  const int ln = lane & 15, lq = lane >> 4;
  const int row = ct * 16 + ln;
  const int k0 = cc * 64 + lq * 8;
  const float* src = (row < BHALF) ? (c_i + (size_t)row * DC) : (c_j + (size_t)(row - BHALF) * DC);
  uint8_t* dst = cbT + (size_t)i2 * 16;

  floatx4 a0 = *(const floatx4*)(src + k0);
  floatx4 a1 = *(const floatx4*)(src + k0 + 4);
  floatx4 b0 = *(const floatx4*)(src + k0 + 32);
  floatx4 b1 = *(const floatx4*)(src + k0 + 36);
  uint4v o;
  o.x = pk4_e4m3(a0[0], a0[1], a0[2], a0[3]);
  o.y = pk4_e4m3(a1[0], a1[1], a1[2], a1[3]);
  o.z = pk4_e4m3(b0[0], b0[1], b0[2], b0[3]);
  o.w = pk4_e4m3(b1[0], b1[1], b1[2], b1[3]);
  *(uint4v*)dst = o;
}

// ---------------- fused symmetric flash-lse: upper-triangle 128x128 blocks ----------------
// R22: cut register-inbound traffic 2x — the one invariant of all ~44us variants
// (B 666 MB + A 333 MB = 1 GB into VGPRs). (a) 64 rows/wave: B halves to 333 MB.
// (b) merged visits (2.03/wave, lazy A-reload on band key change): A -> ~170 MB.
// No LDS, no barriers (R19 base). R20's failure was the scheduler silently targeting
// 4 waves/EU (VGPR capped 128 -> load serialization); fix: amdgpu_waves_per_eu(1,2)
// caps the occupancy target at 2/EU (~256 VGPR budget) + kq-streamed B (8-reg sets,
// no 40-reg up-front batch, no tv array). Grid 2048 single-wave blocks = 2/SIMD
// everywhere; exact-balance split sb*65>>5 (4160 wave-visits); bijective XCD swizzle.
// GO/NO-GO: fused VGPR_Count must read ~240-256, not 128.
__attribute__((amdgpu_flat_work_group_size(64, 64), amdgpu_waves_per_eu(1, 2)))
__global__ void fused_kernel(const uint8_t* __restrict__ zbT, const uint8_t* __restrict__ cbT,
                             float* __restrict__ RP, float* __restrict__ CPW) {
  const int bx = blockIdx.x;
  const int sb = (bx & 7) * 256 + (bx >> 3);     // 2048 = 8*256, bijective
  const int start = (sb * 65) >> 5;               // 4160 wave-visits / 2048 blocks
  const int end   = ((sb + 1) * 65) >> 5;

  const int lane = threadIdx.x;   // 64-thread block = 1 wave
  const int lq   = lane >> 4;
  const int ln   = lane & 15;

  // A operands for 4 row-tiles (64 rows): z 128 VGPR + c 32 VGPR, lazily (re)loaded
  int8v a_z[4][4], a_c[4];
  int curKey = -1;

  for (int wv = start; wv < end; ++wv) {
    const int w = (wv >= 2080) ? 1 : 0;   // half-band
    const int t = wv - w * 2080;

    // band-major triangular decode: t -> (rb, cb), rb <= cb
    const int u = 2079 - t;
    int k = (int)((__builtin_sqrtf(8.0f * (float)u + 1.0f) - 1.0f) * 0.5f);
    while ((k + 1) * (k + 2) / 2 <= u) ++k;
    while (k * (k + 1) / 2 > u) --k;
    const int rb = 63 - k;
    const int cb = 63 - (u - k * (k + 1) / 2);

    const int key = rb * 2 + w;
    if (key != curKey) {                  // rare: ~1.06 loads per block
      curKey = key;
#pragma unroll
      for (int rt_i = 0; rt_i < 4; ++rt_i) {
        const int rt = rb * 8 + 4 * w + rt_i;
        const uint8_t* p = zbT + ((size_t)rt * 512 + lane) * 16;
#pragma unroll
        for (int kq = 0; kq < 4; ++kq)
          a_z[rt_i][kq] = mk8(*(const ulong2v*)(p + (size_t)(2 * kq) * 1024),
                              *(const ulong2v*)(p + (size_t)(2 * kq + 1) * 1024));
        const uint8_t* qc = cbT + ((size_t)rt * 128 + lane) * 16;
        a_c[rt_i] = mk8(*(const ulong2v*)qc, *(const ulong2v*)(qc + 1024));
      }
    }

    const bool diagB = (rb == cb);
    const bool pairB = (cb == rb + 32);
    const int row_w = rb * 128 + w * 64;

    float l_[4][4] = {{0.f,0.f,0.f,0.f},{0.f,0.f,0.f,0.f},{0.f,0.f,0.f,0.f},{0.f,0.f,0.f,0.f}};

#pragma unroll 1
    for (int it8 = 0; it8 < 8; ++it8) {
      const int ct = cb * 8 + it8;
      float lcv = 0.0f;

      // wave-uniform skip: diag blocks, col-tiles fully below this wave's 64 rows
      if (!(diagB && it8 < 4 * w)) {
        const uint8_t* pz = zbT + ((size_t)ct * 512 + lane) * 16;
        const uint8_t* pc = cbT + ((size_t)ct * 128 + lane) * 16;

        const int8v bc = mk8(*(const ulong2v*)pc, *(const ulong2v*)(pc + 1024));
        f32x4 ac[4];
        f32x4 az[4] = {{0.f,0.f,0.f,0.f},{0.f,0.f,0.f,0.f},{0.f,0.f,0.f,0.f},{0.f,0.f,0.f,0.f}};

        __builtin_amdgcn_s_setprio(1);
#pragma unroll
        for (int rt_i = 0; rt_i < 4; ++rt_i) {
          f32x4 zz = {0.f, 0.f, 0.f, 0.f};
          ac[rt_i] = MFMAS(a_c[rt_i], bc, zz);
        }
        // kq-streamed B: one 8-reg bz set live (+1 prefetched by scheduler)
#pragma unroll
        for (int kq = 0; kq < 4; ++kq) {
          const int8v bz = mk8(*(const ulong2v*)(pz + (size_t)(2 * kq) * 1024),
                               *(const ulong2v*)(pz + (size_t)(2 * kq + 1) * 1024));
#pragma unroll
          for (int rt_i = 0; rt_i < 4; ++rt_i)
            az[rt_i] = MFMAS(a_z[rt_i][kq], bz, az[rt_i]);
        }
        __builtin_amdgcn_s_setprio(0);

        const int gc = cb * 128 + it8 * 16 + ln;
#pragma unroll
        for (int rt_i = 0; rt_i < 4; ++rt_i) {
          const int grb = row_w + rt_i * 16 + lq * 4;
          const bool pairTile = pairB && (it8 == 4 * w + rt_i);
#pragma unroll
          for (int r = 0; r < 4; ++r) {
            float tv = fmaxf(ac[rt_i][r], TEMPV);
            float sv = az[rt_i][r] * __builtin_amdgcn_rcpf(tv);
            float e  = __builtin_amdgcn_exp2f(__builtin_fmaf(sv, LOG2E, -FM2));
            if (diagB && gc <= grb + r) e = 0.0f;        // diag + lower half
            if (pairTile && ln == lq * 4 + r) e = 0.0f;  // pair exclusion
            l_[rt_i][r] += e;
            lcv += e;
          }
        }
      }

      // col partial over this wave's 64 rows -> private slot (always written: slots
      // for skipped diag tiles must be 0, workspace is poisoned not zeroed)
      float v = lcv;
      v += __shfl_xor(v, 16);
      v += __shfl_xor(v, 32);
      if (lq == 0)
        CPW[((size_t)(cb * 128 + it8 * 16 + ln)) * 128 + (size_t)rb * 2 + w] = v;
    }

    // RP flush for this visit (xor offs 1..8 stay within the 16-lane ln group)
#pragma unroll
    for (int rt_i = 0; rt_i < 4; ++rt_i)
#pragma unroll
      for (int r = 0; r < 4; ++r) {
        float ll = l_[rt_i][r];
#pragma unroll
        for (int off = 1; off < 16; off <<= 1) ll += __shfl_xor(ll, off);
        if (ln == 0) RP[(size_t)(row_w + rt_i * 16 + lq * 4 + r) * 64 + cb] = ll;
      }
  }
}

// ---------------- finalize: triangular partial merge + pos + reduction ----------------
// Row r (R=r>>7): negsum = sum_{cb>=R} RP[r][cb] + sum_{rb<=R, w} CPW[r][rb*2+w].
__global__ void finalize_kernel(const float* __restrict__ RP, const float* __restrict__ CPW,
                                const float* __restrict__ pos2, float* __restrict__ out) {
  const int tid  = threadIdx.x;
  const int w    = tid >> 6;
  const int lane = tid & 63;
  const int row  = blockIdx.x * 16 + w;
  const int R    = row >> 7;

  float v = 0.0f;
  if (lane >= R) v += RP[(size_t)row * 64 + lane];
  {
    const float2v c2 = *(const float2v*)(CPW + (size_t)row * 128 + lane * 2);
    if (lane <= R) v += c2[0] + c2[1];
  }
#pragma unroll
  for (int off = 1; off < 64; off <<= 1) v += __shfl_xor(v, off);

  __shared__ float red[16];
  if (lane == 0) {
    float pos  = pos2[row & (BHALF - 1)];
    float lneg = FIXM + __logf(v);
    float hi = fmaxf(lneg, pos), lo = fminf(lneg, pos);
    float lse = hi + __logf(1.0f + __expf(lo - hi));
    red[w] = lse - pos;
  }
  __syncthreads();
  if (tid == 0) {
    float s = 0.0f;
#pragma unroll
    for (int i = 0; i < 16; ++i) s += red[i];
    atomicAdd(out, s * (1.0f / NTOT));
  }
}

extern "C" void kernel_launch(void* const* d_in, const int* in_sizes, int n_in,
                              void* d_out, int out_size, void* d_ws, size_t ws_size,
                              hipStream_t stream) {
  const float* z_i = (const float*)d_in[0];
  const float* z_j = (const float*)d_in[1];
  const float* c_i = (const float*)d_in[2];
  const float* c_j = (const float*)d_in[3];

  uint8_t* zbT = (uint8_t*)d_ws;                        // 4 MB fp8 z (tiled)
  uint8_t* cbT = zbT + (size_t)NTOT * DZ;               // 1 MB fp8 c (tiled)
  float* RP   = (float*)(cbT + (size_t)NTOT * DC);      // 2 MB
  float* CPW  = RP + (size_t)NTOT * 64;                 // 4 MB (per-wave col slots)
  float* pos2 = CPW + (size_t)NTOT * 128;               // 16 KB

  convert_kernel<<<1280, 256, 0, stream>>>(z_i, z_j, c_i, c_j, zbT, cbT, pos2, (float*)d_out);
  fused_kernel<<<2048, 64, 0, stream>>>(zbT, cbT, RP, CPW);
  finalize_kernel<<<512, 1024, 0, stream>>>(RP, CPW, pos2, (float*)d_out);
}

// Round 7
// 177.611 us; speedup vs baseline: 1.1657x; 1.1657x over previous
//
#include <hip/hip_runtime.h>
#include <stdint.h>

#define NTOT 8192
#define BHALF 4096
#define DZ 512
#define DC 128
#define TEMPV 0.5f
#define FIXM 16.0f
#define LOG2E 1.44269504f
#define FM2 23.08312065f   // FIXM * LOG2E
#define SCALE1 0x7F7F7F7F  // e8m0 unit scales

typedef __attribute__((ext_vector_type(4))) float f32x4;
typedef __attribute__((ext_vector_type(4))) float floatx4;
typedef __attribute__((ext_vector_type(2))) unsigned long ulong2v;  // 16B chunk
typedef __attribute__((ext_vector_type(8))) int int8v;              // 32B MFMA operand
typedef __attribute__((ext_vector_type(4))) unsigned int uint4v;

// MX-scaled fp8 MFMA, K=128, unit scales. cbsz=0/blgp=0 -> FP8 e4m3 A and B.
#define MFMAS(a, b, c) \
  __builtin_amdgcn_mfma_scale_f32_16x16x128_f8f6f4((a), (b), (c), 0, 0, 0, SCALE1, 0, SCALE1)

__device__ __forceinline__ uint32_t pk4_e4m3(float f0, float f1, float f2, float f3) {
  int w = 0;
  w = __builtin_amdgcn_cvt_pk_fp8_f32(f0, f1, w, false);
  w = __builtin_amdgcn_cvt_pk_fp8_f32(f2, f3, w, true);
  return (uint32_t)w;
}

__device__ __forceinline__ int8v mk8(ulong2v lo, ulong2v hi) {
  int8v r;
  ((ulong2v*)&r)[0] = lo;
  ((ulong2v*)&r)[1] = hi;
  return r;
}

// ---------------- convert: fp32 -> fp8 e4m3 (frag-pair-tiled) + fused pos dots ----------------
// R21 single-pass version (verified): one wave per pair-row p; z read once; pos dot via
// shfl_xor(.,32) cross-half products. c-section unchanged verified mapping.
__global__ void convert_kernel(const float* __restrict__ z_i, const float* __restrict__ z_j,
                               const float* __restrict__ c_i, const float* __restrict__ c_j,
                               uint8_t* __restrict__ zbT, uint8_t* __restrict__ cbT,
                               float* __restrict__ pos2, float* __restrict__ out) {
  if (blockIdx.x < 1024) {
    const int p    = blockIdx.x * 4 + (threadIdx.x >> 6);   // 0..4095
    const int lane = threadIdx.x & 63;
    const int half = lane >> 5;          // 0: z_i row p, 1: z_j row p (global row p+4096)
    const int l    = lane & 31;
    const int cc   = l >> 2;
    const int lq   = l & 3;
    const int k0   = cc * 64 + lq * 8;

    const float* src = half ? (z_j + (size_t)p * DZ) : (z_i + (size_t)p * DZ);
    floatx4 a0 = *(const floatx4*)(src + k0);
    floatx4 a1 = *(const floatx4*)(src + k0 + 4);
    floatx4 b0 = *(const floatx4*)(src + k0 + 32);
    floatx4 b1 = *(const floatx4*)(src + k0 + 36);

    uint4v o;
    o.x = pk4_e4m3(a0[0], a0[1], a0[2], a0[3]);
    o.y = pk4_e4m3(a1[0], a1[1], a1[2], a1[3]);
    o.z = pk4_e4m3(b0[0], b0[1], b0[2], b0[3]);
    o.w = pk4_e4m3(b1[0], b1[1], b1[2], b1[3]);
    const int row = half ? (p + BHALF) : p;
    const size_t ci = (((size_t)(row >> 4) * 8 + cc) * 64 + (size_t)lq * 16 + (row & 15));
    *(uint4v*)(zbT + ci * 16) = o;

    float d = 0.0f;
#pragma unroll
    for (int m = 0; m < 4; ++m) d = __builtin_fmaf(a0[m], __shfl_xor(a0[m], 32), d);
#pragma unroll
    for (int m = 0; m < 4; ++m) d = __builtin_fmaf(a1[m], __shfl_xor(a1[m], 32), d);
#pragma unroll
    for (int m = 0; m < 4; ++m) d = __builtin_fmaf(b0[m], __shfl_xor(b0[m], 32), d);
#pragma unroll
    for (int m = 0; m < 4; ++m) d = __builtin_fmaf(b1[m], __shfl_xor(b1[m], 32), d);
#pragma unroll
    for (int off = 1; off < 32; off <<= 1) d += __shfl_xor(d, off);
    if (lane == 0) pos2[p] = 2.0f * d;
    return;
  }

  // c-section: blocks 1024..1279, verified chunk mapping (i2 in [0, 65536))
  if (blockIdx.x == 1024 && threadIdx.x == 0) out[0] = 0.0f;
  const int i2   = (blockIdx.x - 1024) * 256 + threadIdx.x;
  const int lane = i2 & 63, g = i2 >> 6;
  const int ct = g >> 1, cc = g & 1;
  const int ln = lane & 15, lq = lane >> 4;
  const int row = ct * 16 + ln;
  const int k0 = cc * 64 + lq * 8;
  const float* src = (row < BHALF) ? (c_i + (size_t)row * DC) : (c_j + (size_t)(row - BHALF) * DC);
  uint8_t* dst = cbT + (size_t)i2 * 16;

  floatx4 a0 = *(const floatx4*)(src + k0);
  floatx4 a1 = *(const floatx4*)(src + k0 + 4);
  floatx4 b0 = *(const floatx4*)(src + k0 + 32);
  floatx4 b1 = *(const floatx4*)(src + k0 + 36);
  uint4v o;
  o.x = pk4_e4m3(a0[0], a0[1], a0[2], a0[3]);
  o.y = pk4_e4m3(a1[0], a1[1], a1[2], a1[3]);
  o.z = pk4_e4m3(b0[0], b0[1], b0[2], b0[3]);
  o.w = pk4_e4m3(b1[0], b1[1], b1[2], b1[3]);
  *(uint4v*)dst = o;
}

// ---------------- fused symmetric flash-lse: upper-triangle 128x128 blocks ----------------
// R23 = R19 structure (verified ~44 us: no LDS, no barriers, 1 wave/block, B from L2,
// per-wave CPW slots) + occupancy push: R4/R6 proved perf tracks OCCUPANCY (2 waves/
// SIMD -> 132 us; ~3 -> 44 us), so target the 128-VGPR tier = 4 waves/SIMD (16/CU).
// Register plan: a_z 64 + a_c 16 resident, bz STREAMED per-kq (8 regs, was 40-reg
// batch), az+tv 16, l_ 8, addr ~12 => peak ~124-132 at the 128 cap (unlike R4's
// need-250-cap-128 catastrophic spill). The exposed per-kq load->MFMA latency is
// what the 4th wave hides. GO/NO-GO: VGPR_Count ~124-128 AND no WRITE_SIZE growth.
__launch_bounds__(64, 4)
__global__ void fused_kernel(const uint8_t* __restrict__ zbT, const uint8_t* __restrict__ cbT,
                             float* __restrict__ RP, float* __restrict__ CPW) {
  // 8320 = 8 * 1040 exactly -> bijective XCD-chunk swizzle
  const int bx  = blockIdx.x;
  const int swz = (bx & 7) * 1040 + (bx >> 3);
  const int t   = swz >> 2;       // visit 0..2079
  const int w   = swz & 3;        // band-quarter 0..3

  // band-major triangular decode: t -> (rb, cb), rb <= cb
  const int u = 2079 - t;
  int k = (int)((__builtin_sqrtf(8.0f * (float)u + 1.0f) - 1.0f) * 0.5f);
  while ((k + 1) * (k + 2) / 2 <= u) ++k;
  while (k * (k + 1) / 2 > u) --k;
  const int rb = 63 - k;
  const int cb = 63 - (u - k * (k + 1) / 2);
  const bool diagBlk = (rb == cb);
  const bool pairBlk = (cb == rb + 32);

  const int lane = threadIdx.x;   // 64-thread block = 1 wave
  const int lq   = lane >> 4;
  const int ln   = lane & 15;
  const int row_w = rb * 128 + w * 32;

  // A operands for this wave's 2 row-tiles (resident): z 64 VGPR + c 16 VGPR
  int8v a_z[2][4], a_c[2];
#pragma unroll
  for (int rt_i = 0; rt_i < 2; ++rt_i) {
    const int rt = rb * 8 + 2 * w + rt_i;
    const uint8_t* p = zbT + ((size_t)rt * 512 + lane) * 16;
#pragma unroll
    for (int kq = 0; kq < 4; ++kq)
      a_z[rt_i][kq] = mk8(*(const ulong2v*)(p + (size_t)(2 * kq) * 1024),
                          *(const ulong2v*)(p + (size_t)(2 * kq + 1) * 1024));
    const uint8_t* qc = cbT + ((size_t)rt * 128 + lane) * 16;
    a_c[rt_i] = mk8(*(const ulong2v*)qc, *(const ulong2v*)(qc + 1024));
  }

  float l_[2][4] = {{0.f, 0.f, 0.f, 0.f}, {0.f, 0.f, 0.f, 0.f}};

#pragma unroll
  for (int it8 = 0; it8 < 8; ++it8) {
    const int ct = cb * 8 + it8;
    float lcv = 0.0f;

    // wave-uniform skip: diag blocks, col-tiles fully below this wave's 32 rows
    if (!(diagBlk && it8 < 2 * w)) {
      const uint8_t* pz = zbT + ((size_t)ct * 512 + lane) * 16;
      const uint8_t* pc = cbT + ((size_t)ct * 128 + lane) * 16;

      // c path first: its MFMA + rcp gives the scheduler work to overlap the
      // first streamed bz load
      const int8v bc = mk8(*(const ulong2v*)pc, *(const ulong2v*)(pc + 1024));

      f32x4 ac[2];
      __builtin_amdgcn_s_setprio(1);
      {
        f32x4 zz0 = {0.f, 0.f, 0.f, 0.f};
        f32x4 zz1 = {0.f, 0.f, 0.f, 0.f};
        ac[0] = MFMAS(a_c[0], bc, zz0);
        ac[1] = MFMAS(a_c[1], bc, zz1);
      }
      f32x4 tv[2];
#pragma unroll
      for (int rt_i = 0; rt_i < 2; ++rt_i)
#pragma unroll
        for (int r = 0; r < 4; ++r)
          tv[rt_i][r] = __builtin_amdgcn_rcpf(fmaxf(ac[rt_i][r], TEMPV));

      f32x4 az[2] = {{0.f, 0.f, 0.f, 0.f}, {0.f, 0.f, 0.f, 0.f}};
      // kq-streamed B: ONE 8-reg bz live at a time (keeps peak VGPR under the
      // 128 tier; the exposed load latency is hidden by the 4 waves/SIMD)
#pragma unroll
      for (int kq = 0; kq < 4; ++kq) {
        const int8v bz = mk8(*(const ulong2v*)(pz + (size_t)(2 * kq) * 1024),
                             *(const ulong2v*)(pz + (size_t)(2 * kq + 1) * 1024));
        az[0] = MFMAS(a_z[0][kq], bz, az[0]);
        az[1] = MFMAS(a_z[1][kq], bz, az[1]);
      }
      __builtin_amdgcn_s_setprio(0);

      const int gc = cb * 128 + it8 * 16 + ln;
#pragma unroll
      for (int rt_i = 0; rt_i < 2; ++rt_i) {
        const int grb = row_w + rt_i * 16 + lq * 4;
        const bool pairTile = pairBlk && (it8 == 2 * w + rt_i);
#pragma unroll
        for (int r = 0; r < 4; ++r) {
          float sv = az[rt_i][r] * tv[rt_i][r];
          float e  = __builtin_amdgcn_exp2f(__builtin_fmaf(sv, LOG2E, -FM2));
          if (diagBlk && gc <= grb + r) e = 0.0f;        // diag + lower half
          if (pairTile && ln == lq * 4 + r) e = 0.0f;    // pair exclusion
          l_[rt_i][r] += e;
          lcv += e;
        }
      }
    }

    // col partial for this tile over this wave's 32 rows -> private slot (always
    // written: slots for skipped diag tiles must be 0, workspace is poisoned)
    float v = lcv;
    v += __shfl_xor(v, 16);
    v += __shfl_xor(v, 32);
    if (lq == 0)
      CPW[((size_t)(cb * 128 + it8 * 16 + ln)) * 256 + (size_t)rb * 4 + w] = v;
  }

  // row partials -> RP[row][cb] (xor offs 1..8 stay within the 16-lane ln group)
#pragma unroll
  for (int rt_i = 0; rt_i < 2; ++rt_i)
#pragma unroll
    for (int r = 0; r < 4; ++r) {
      float ll = l_[rt_i][r];
#pragma unroll
      for (int off = 1; off < 16; off <<= 1) ll += __shfl_xor(ll, off);
      if (ln == 0) RP[(size_t)(row_w + rt_i * 16 + lq * 4 + r) * 64 + cb] = ll;
    }
}

// ---------------- finalize: triangular partial merge + pos + reduction ----------------
// Row r (R=r>>7): negsum = sum_{cb>=R} RP[r][cb] + sum_{rb<=R, w} CPW[r][rb*4+w].
// CPW read as float4/lane (lane l covers rb=l, 4 w-slots) -> 1 KB coalesced per wave.
__global__ void finalize_kernel(const float* __restrict__ RP, const float* __restrict__ CPW,
                                const float* __restrict__ pos2, float* __restrict__ out) {
  const int tid  = threadIdx.x;
  const int w    = tid >> 6;
  const int lane = tid & 63;
  const int row  = blockIdx.x * 16 + w;
  const int R    = row >> 7;

  float v = 0.0f;
  if (lane >= R) v += RP[(size_t)row * 64 + lane];
  {
    const floatx4 c4 = *(const floatx4*)(CPW + (size_t)row * 256 + lane * 4);
    if (lane <= R) v += c4[0] + c4[1] + c4[2] + c4[3];
  }
#pragma unroll
  for (int off = 1; off < 64; off <<= 1) v += __shfl_xor(v, off);

  __shared__ float red[16];
  if (lane == 0) {
    float pos  = pos2[row & (BHALF - 1)];
    float lneg = FIXM + __logf(v);
    float hi = fmaxf(lneg, pos), lo = fminf(lneg, pos);
    float lse = hi + __logf(1.0f + __expf(lo - hi));
    red[w] = lse - pos;
  }
  __syncthreads();
  if (tid == 0) {
    float s = 0.0f;
#pragma unroll
    for (int i = 0; i < 16; ++i) s += red[i];
    atomicAdd(out, s * (1.0f / NTOT));
  }
}

extern "C" void kernel_launch(void* const* d_in, const int* in_sizes, int n_in,
                              void* d_out, int out_size, void* d_ws, size_t ws_size,
                              hipStream_t stream) {
  const float* z_i = (const float*)d_in[0];
  const float* z_j = (const float*)d_in[1];
  const float* c_i = (const float*)d_in[2];
  const float* c_j = (const float*)d_in[3];

  uint8_t* zbT = (uint8_t*)d_ws;                        // 4 MB fp8 z (tiled)
  uint8_t* cbT = zbT + (size_t)NTOT * DZ;               // 1 MB fp8 c (tiled)
  float* RP   = (float*)(cbT + (size_t)NTOT * DC);      // 2 MB
  float* CPW  = RP + (size_t)NTOT * 64;                 // 8 MB (per-wave col slots)
  float* pos2 = CPW + (size_t)NTOT * 256;               // 16 KB

  convert_kernel<<<1280, 256, 0, stream>>>(z_i, z_j, c_i, c_j, zbT, cbT, pos2, (float*)d_out);
  fused_kernel<<<8320, 64, 0, stream>>>(zbT, cbT, RP, CPW);
  finalize_kernel<<<512, 1024, 0, stream>>>(RP, CPW, pos2, (float*)d_out);
}

// Round 8
// 116.286 us; speedup vs baseline: 1.7805x; 1.5274x over previous
//
#include <hip/hip_runtime.h>
#include <stdint.h>

#define NTOT 8192
#define BHALF 4096
#define DZ 512
#define DC 128
#define TEMPV 0.5f
#define FIXM 16.0f
#define LOG2E 1.44269504f
#define FM2 23.08312065f   // FIXM * LOG2E
#define SCALE1 0x7F7F7F7F  // e8m0 unit scales

typedef __attribute__((ext_vector_type(4))) float f32x4;
typedef __attribute__((ext_vector_type(4))) float floatx4;
typedef __attribute__((ext_vector_type(2))) unsigned long ulong2v;  // 16B chunk
typedef __attribute__((ext_vector_type(8))) int int8v;              // 32B MFMA operand
typedef __attribute__((ext_vector_type(4))) unsigned int uint4v;

// MX-scaled fp8 MFMA, K=128, unit scales. cbsz=0/blgp=0 -> FP8 e4m3 A and B.
#define MFMAS(a, b, c) \
  __builtin_amdgcn_mfma_scale_f32_16x16x128_f8f6f4((a), (b), (c), 0, 0, 0, SCALE1, 0, SCALE1)

// counted vmcnt + raw barrier (no vmcnt(0) drain in the main loop)
#define WAITV(N) asm volatile("s_waitcnt vmcnt(" #N ")" ::: "memory")
#define BARRIER() asm volatile("s_barrier" ::: "memory")

__device__ __forceinline__ uint32_t pk4_e4m3(float f0, float f1, float f2, float f3) {
  int w = 0;
  w = __builtin_amdgcn_cvt_pk_fp8_f32(f0, f1, w, false);
  w = __builtin_amdgcn_cvt_pk_fp8_f32(f2, f3, w, true);
  return (uint32_t)w;
}

__device__ __forceinline__ int8v mk8(ulong2v lo, ulong2v hi) {
  int8v r;
  ((ulong2v*)&r)[0] = lo;
  ((ulong2v*)&r)[1] = hi;
  return r;
}

// ---------------- convert: fp32 -> fp8 e4m3 (frag-pair-tiled) + fused pos dots ----------------
// R21 single-pass version (measured-equal to two-pass, less HBM): one wave per pair-row;
// z read once; pos dot via shfl_xor(.,32) cross-half products. c-section verified mapping.
__global__ void convert_kernel(const float* __restrict__ z_i, const float* __restrict__ z_j,
                               const float* __restrict__ c_i, const float* __restrict__ c_j,
                               uint8_t* __restrict__ zbT, uint8_t* __restrict__ cbT,
                               float* __restrict__ pos2, float* __restrict__ out) {
  if (blockIdx.x < 1024) {
    const int p    = blockIdx.x * 4 + (threadIdx.x >> 6);   // 0..4095
    const int lane = threadIdx.x & 63;
    const int half = lane >> 5;          // 0: z_i row p, 1: z_j row p (global row p+4096)
    const int l    = lane & 31;
    const int cc   = l >> 2;
    const int lq   = l & 3;
    const int k0   = cc * 64 + lq * 8;

    const float* src = half ? (z_j + (size_t)p * DZ) : (z_i + (size_t)p * DZ);
    floatx4 a0 = *(const floatx4*)(src + k0);
    floatx4 a1 = *(const floatx4*)(src + k0 + 4);
    floatx4 b0 = *(const floatx4*)(src + k0 + 32);
    floatx4 b1 = *(const floatx4*)(src + k0 + 36);

    uint4v o;
    o.x = pk4_e4m3(a0[0], a0[1], a0[2], a0[3]);
    o.y = pk4_e4m3(a1[0], a1[1], a1[2], a1[3]);
    o.z = pk4_e4m3(b0[0], b0[1], b0[2], b0[3]);
    o.w = pk4_e4m3(b1[0], b1[1], b1[2], b1[3]);
    const int row = half ? (p + BHALF) : p;
    const size_t ci = (((size_t)(row >> 4) * 8 + cc) * 64 + (size_t)lq * 16 + (row & 15));
    *(uint4v*)(zbT + ci * 16) = o;

    float d = 0.0f;
#pragma unroll
    for (int m = 0; m < 4; ++m) d = __builtin_fmaf(a0[m], __shfl_xor(a0[m], 32), d);
#pragma unroll
    for (int m = 0; m < 4; ++m) d = __builtin_fmaf(a1[m], __shfl_xor(a1[m], 32), d);
#pragma unroll
    for (int m = 0; m < 4; ++m) d = __builtin_fmaf(b0[m], __shfl_xor(b0[m], 32), d);
#pragma unroll
    for (int m = 0; m < 4; ++m) d = __builtin_fmaf(b1[m], __shfl_xor(b1[m], 32), d);
#pragma unroll
    for (int off = 1; off < 32; off <<= 1) d += __shfl_xor(d, off);
    if (lane == 0) pos2[p] = 2.0f * d;
    return;
  }

  // c-section: blocks 1024..1279, verified chunk mapping (i2 in [0, 65536))
  if (blockIdx.x == 1024 && threadIdx.x == 0) out[0] = 0.0f;
  const int i2   = (blockIdx.x - 1024) * 256 + threadIdx.x;
  const int lane = i2 & 63, g = i2 >> 6;
  const int ct = g >> 1, cc = g & 1;
  const int ln = lane & 15, lq = lane >> 4;
  const int row = ct * 16 + ln;
  const int k0 = cc * 64 + lq * 8;
  const float* src = (row < BHALF) ? (c_i + (size_t)row * DC) : (c_j + (size_t)(row - BHALF) * DC);
  uint8_t* dst = cbT + (size_t)i2 * 16;

  floatx4 a0 = *(const floatx4*)(src + k0);
  floatx4 a1 = *(const floatx4*)(src + k0 + 4);
  floatx4 b0 = *(const floatx4*)(src + k0 + 32);
  floatx4 b1 = *(const floatx4*)(src + k0 + 36);
  uint4v o;
  o.x = pk4_e4m3(a0[0], a0[1], a0[2], a0[3]);
  o.y = pk4_e4m3(a1[0], a1[1], a1[2], a1[3]);
  o.z = pk4_e4m3(b0[0], b0[1], b0[2], b0[3]);
  o.w = pk4_e4m3(b1[0], b1[1], b1[2], b1[3]);
  *(uint4v*)dst = o;
}

// stage col-tile ct into buf (4-wave version): wave w stages z chunk-groups 2w, 2w+1;
// waves 0,1 additionally stage the c chunk-groups. L = 3 loads (w<2) or 2 loads (w>=2).
__device__ __forceinline__ void stage4(const uint8_t* __restrict__ zbT,
                                       const uint8_t* __restrict__ cbT,
                                       uint8_t* buf, int ct, int w, int lane) {
  const uint8_t* src = zbT + (((size_t)ct * 8 + 2 * w) * 64 + lane) * 16;
  __builtin_amdgcn_global_load_lds((const __attribute__((address_space(1))) void*)src,
                                   (__attribute__((address_space(3))) void*)(buf + 2 * w * 1024),
                                   16, 0, 0);
  __builtin_amdgcn_global_load_lds((const __attribute__((address_space(1))) void*)(src + 1024),
                                   (__attribute__((address_space(3))) void*)(buf + (2 * w + 1) * 1024),
                                   16, 0, 0);
  if (w < 2) {
    const uint8_t* srcc = cbT + (((size_t)ct * 2 + w) * 64 + lane) * 16;
    __builtin_amdgcn_global_load_lds((const __attribute__((address_space(1))) void*)srcc,
                                     (__attribute__((address_space(3))) void*)(buf + 8192 + w * 1024),
                                     16, 0, 0);
  }
}

// ---------------- fused symmetric flash-lse: upper-triangle 128x128 blocks ----------------
// R24 = byte-identical revert to the R1-MEASURED 43.9us kernel (4 waves x 32 rows,
// 3 LDS buffers, counted vmcnt, (256,3) -> ~156 VGPR / 3 waves/SIMD), plus ONE edit:
// the wave-uniform diag/pair classification is hoisted OUT of the per-element loops.
// 1984/2080 blocks (95.4%) now run a mask-free epilogue (7 VALU/elem vs ~10).
// R4/R6/R7 lockdown: this body needs ~150-160 VGPR; capping to 128/64 spills
// catastrophically, forcing 256 runs 2 waves/SIMD and latency-binds. Do not touch
// the occupancy point again.
__launch_bounds__(256, 3)
__global__ void fused_kernel(const uint8_t* __restrict__ zbT, const uint8_t* __restrict__ cbT,
                             float* __restrict__ RP, float* __restrict__ CP) {
  __shared__ __align__(16) uint8_t S[3][10240];   // 3 x (8 KB z + 2 KB c)
  __shared__ float colbuf[4 * 128];               // 2 KB

  // triangular decode: t -> (rb, cb), rb <= cb, 2080 blocks
  const int t = blockIdx.x;
  const int u = 2079 - t;
  int k = (int)((__builtin_sqrtf(8.0f * (float)u + 1.0f) - 1.0f) * 0.5f);
  while ((k + 1) * (k + 2) / 2 <= u) ++k;
  while (k * (k + 1) / 2 > u) --k;
  const int j = u - k * (k + 1) / 2;
  const int rb = 63 - k;
  const int cb = 63 - j;
  const bool diagBlk = (rb == cb);
  const bool pairBlk = (cb == rb + 32);

  const int tid  = threadIdx.x;
  const int w    = tid >> 6;      // 0..3
  const int lane = tid & 63;
  const int lq   = lane >> 4;
  const int ln   = lane & 15;

  const int row_w = rb * 128 + w * 32;     // wave's 32 rows (2 row-tiles)

  // A operands for 2 row-tiles: z = 2 x 4 x v8i32, c = 2 x v8i32 (~80 VGPR resident)
  int8v a_z[2][4], a_c[2];
#pragma unroll
  for (int rt_i = 0; rt_i < 2; ++rt_i) {
    const int rt = rb * 8 + 2 * w + rt_i;
    const uint8_t* p = zbT + ((size_t)rt * 512 + lane) * 16;
#pragma unroll
    for (int kq = 0; kq < 4; ++kq)
      a_z[rt_i][kq] = mk8(*(const ulong2v*)(p + (size_t)(2 * kq) * 1024),
                          *(const ulong2v*)(p + (size_t)(2 * kq + 1) * 1024));
    const uint8_t* qc = cbT + ((size_t)rt * 128 + lane) * 16;
    a_c[rt_i] = mk8(*(const ulong2v*)qc, *(const ulong2v*)(qc + 1024));
  }

  float l_[2][4] = {{0.f, 0.f, 0.f, 0.f}, {0.f, 0.f, 0.f, 0.f}};

  const int ct_base = cb * 8;
  stage4(zbT, cbT, &S[0][0], ct_base + 0, w, lane);
  stage4(zbT, cbT, &S[1][0], ct_base + 1, w, lane);

#pragma unroll
  for (int it = 0; it < 8; ++it) {
    // issue prefetch for tile it+2, then wait (counted) until tile it has landed.
    // L = 3 (w<2) or 2 (w>=2) loads per stage; outstanding after issue = 3 stages.
    if (it < 6) {
      stage4(zbT, cbT, &S[(it + 2) % 3][0], ct_base + it + 2, w, lane);
      if (w < 2) { WAITV(6); } else { WAITV(4); }
    } else if (it == 6) {
      if (w < 2) { WAITV(3); } else { WAITV(2); }
    } else {
      WAITV(0);
    }
    BARRIER();   // all waves' tile-it stages landed

    float lcv = 0.0f;
    // wave-uniform skip: diag blocks, col-tiles fully below this wave's 32 rows
    if (!(diagBlk && it < 2 * w)) {
      const uint8_t* zb  = &S[it % 3][0];
      const uint8_t* cS_ = zb + 8192;

      f32x4 ac[2] = {{0.f, 0.f, 0.f, 0.f}, {0.f, 0.f, 0.f, 0.f}};
      f32x4 az[2] = {{0.f, 0.f, 0.f, 0.f}, {0.f, 0.f, 0.f, 0.f}};

      __builtin_amdgcn_s_setprio(1);
      {
        const int8v bc = mk8(*(const ulong2v*)(cS_ + lane * 16),
                             *(const ulong2v*)(cS_ + 1024 + lane * 16));
        ac[0] = MFMAS(a_c[0], bc, ac[0]);
        ac[1] = MFMAS(a_c[1], bc, ac[1]);
      }
#pragma unroll
      for (int kq = 0; kq < 4; ++kq) {
        const int8v b = mk8(*(const ulong2v*)(zb + (2 * kq) * 1024 + lane * 16),
                            *(const ulong2v*)(zb + (2 * kq + 1) * 1024 + lane * 16));
        az[0] = MFMAS(a_z[0][kq], b, az[0]);
        az[1] = MFMAS(a_z[1][kq], b, az[1]);
      }
      __builtin_amdgcn_s_setprio(0);

      // epilogue: three wave-uniform specializations (hot path = mask-free)
      if (!diagBlk && !pairBlk) {
#pragma unroll
        for (int rt_i = 0; rt_i < 2; ++rt_i)
#pragma unroll
          for (int r = 0; r < 4; ++r) {
            float tv = fmaxf(ac[rt_i][r], TEMPV);
            float sv = az[rt_i][r] * __builtin_amdgcn_rcpf(tv);
            float e  = __builtin_amdgcn_exp2f(__builtin_fmaf(sv, LOG2E, -FM2));
            l_[rt_i][r] += e;
            lcv += e;
          }
      } else if (diagBlk) {
        const int gc = cb * 128 + it * 16 + ln;
#pragma unroll
        for (int rt_i = 0; rt_i < 2; ++rt_i) {
          const int grb = row_w + rt_i * 16 + lq * 4;
#pragma unroll
          for (int r = 0; r < 4; ++r) {
            float tv = fmaxf(ac[rt_i][r], TEMPV);
            float sv = az[rt_i][r] * __builtin_amdgcn_rcpf(tv);
            float e  = __builtin_amdgcn_exp2f(__builtin_fmaf(sv, LOG2E, -FM2));
            if (gc <= grb + r) e = 0.0f;                 // diag + lower half
            l_[rt_i][r] += e;
            lcv += e;
          }
        }
      } else {   // pairBlk
#pragma unroll
        for (int rt_i = 0; rt_i < 2; ++rt_i) {
          const bool pairTile = (it == 2 * w + rt_i);
#pragma unroll
          for (int r = 0; r < 4; ++r) {
            float tv = fmaxf(ac[rt_i][r], TEMPV);
            float sv = az[rt_i][r] * __builtin_amdgcn_rcpf(tv);
            float e  = __builtin_amdgcn_exp2f(__builtin_fmaf(sv, LOG2E, -FM2));
            if (pairTile && ln == lq * 4 + r) e = 0.0f;  // pair exclusion
            l_[rt_i][r] += e;
            lcv += e;
          }
        }
      }
    }

    // col partial for this tile: reduce over lq, store (unique slot, pre-barrier)
    float v = lcv;
    v += __shfl_xor(v, 16);
    v += __shfl_xor(v, 32);
    if (lq == 0) colbuf[w * 128 + it * 16 + ln] = v;

    BARRIER();   // all waves done reading S[it%3] before it is re-staged next iter
  }

  __syncthreads();   // full drain (colbuf ds_writes) before cross-wave read

  // row partials -> RP[row][cb] (xor offs 1..8 stay within the 16-lane ln group)
#pragma unroll
  for (int rt_i = 0; rt_i < 2; ++rt_i)
#pragma unroll
    for (int r = 0; r < 4; ++r) {
      float ll = l_[rt_i][r];
#pragma unroll
      for (int off = 1; off < 16; off <<= 1) ll += __shfl_xor(ll, off);
      if (ln == 0) RP[(size_t)(row_w + rt_i * 16 + lq * 4 + r) * 64 + cb] = ll;
    }

  // col partials: sum the 4 per-wave rows of colbuf -> CP[col][rb]
  if (tid < 128) {
    float s = 0.0f;
#pragma unroll
    for (int ww = 0; ww < 4; ++ww) s += colbuf[ww * 128 + tid];
    CP[(size_t)(cb * 128 + tid) * 64 + rb] = s;
  }
}

// ---------------- finalize: triangular partial merge + pos + reduction ----------------
__global__ void finalize_kernel(const float* __restrict__ RP, const float* __restrict__ CP,
                                const float* __restrict__ pos2, float* __restrict__ out) {
  const int tid  = threadIdx.x;
  const int w    = tid >> 6;
  const int lane = tid & 63;
  const int row  = blockIdx.x * 16 + w;
  const int R    = row >> 7;

  float v = 0.0f;
  if (lane >= R) v += RP[(size_t)row * 64 + lane];
  if (lane <= R) v += CP[(size_t)row * 64 + lane];
#pragma unroll
  for (int off = 1; off < 64; off <<= 1) v += __shfl_xor(v, off);

  __shared__ float red[16];
  if (lane == 0) {
    float pos  = pos2[row & (BHALF - 1)];
    float lneg = FIXM + __logf(v);
    float hi = fmaxf(lneg, pos), lo = fminf(lneg, pos);
    float lse = hi + __logf(1.0f + __expf(lo - hi));
    red[w] = lse - pos;
  }
  __syncthreads();
  if (tid == 0) {
    float s = 0.0f;
#pragma unroll
    for (int i = 0; i < 16; ++i) s += red[i];
    atomicAdd(out, s * (1.0f / NTOT));
  }
}

extern "C" void kernel_launch(void* const* d_in, const int* in_sizes, int n_in,
                              void* d_out, int out_size, void* d_ws, size_t ws_size,
                              hipStream_t stream) {
  const float* z_i = (const float*)d_in[0];
  const float* z_j = (const float*)d_in[1];
  const float* c_i = (const float*)d_in[2];
  const float* c_j = (const float*)d_in[3];

  uint8_t* zbT = (uint8_t*)d_ws;                        // 4 MB fp8 z (tiled)
  uint8_t* cbT = zbT + (size_t)NTOT * DZ;               // 1 MB fp8 c (tiled)
  float* RP   = (float*)(cbT + (size_t)NTOT * DC);      // 2 MB
  float* CP   = RP + (size_t)NTOT * 64;                 // 2 MB
  float* pos2 = CP + (size_t)NTOT * 64;                 // 16 KB

  convert_kernel<<<1280, 256, 0, stream>>>(z_i, z_j, c_i, c_j, zbT, cbT, pos2, (float*)d_out);
  fused_kernel<<<2080, 256, 0, stream>>>(zbT, cbT, RP, CP);
  finalize_kernel<<<512, 1024, 0, stream>>>(RP, CP, pos2, (float*)d_out);
}